// Round 13
// baseline (906.242 us; speedup 1.0000x reference)
//
#include <hip/hip_runtime.h>

// MeshGraphNet rollout, round 13: hybrid aggregation.
// - ge_edge scatters ONLY the s0 side (sorted -> ~1-2 segment pk-bf16 atomics
//   per thread; 10x fewer atomic ops than r12, which was L2-atomic-rate bound)
// - s1 side is a CSR gather fused into gn's MODE-4 staging (plain reads, f32 acc)
// - mp1 ge_edge stores h2 in-place into e32ee (row-exclusive per block)
// Otherwise round 12: BN folded into consumer staging, factored ge, slotted
// stats, s0-sorted edges. N=20000, E=320000, ROLL=2, MP=2.

constexpr int NN = 20000;
constexpr int NE = 320000;
constexpr int NSLOT = 32;        // stat sub-slots (de-contend atomics)
constexpr int SSTR = 512;        // floats per sub-slot: [sum(<=256) | sumsq(<=256)]

typedef __attribute__((ext_vector_type(8))) short short8;
typedef __attribute__((ext_vector_type(4))) float f32x4;

__device__ __forceinline__ float act_elu(float x) { return x > 0.f ? x : __expf(x) - 1.f; }
__device__ __forceinline__ unsigned short f2bf(float f) {
  unsigned u = __builtin_bit_cast(unsigned, f);
  return (unsigned short)((u + 0x7FFFu + ((u >> 16) & 1u)) >> 16);
}
__device__ __forceinline__ float bf2f(unsigned short h) {
  unsigned u = ((unsigned)h) << 16; return __builtin_bit_cast(float, u);
}
// packed bf16 atomic add: adds (a,b) to two consecutive bf16 at addr (4B aligned)
__device__ __forceinline__ void atomic_pk_bf16(unsigned short* addr, float a, float b) {
  unsigned v = (unsigned)f2bf(a) | ((unsigned)f2bf(b) << 16);
  asm volatile("global_atomic_pk_add_bf16 %0, %1, off"
               :: "v"(addr), "v"(v) : "memory");
}

// ---------------------------------------------------------------------------
// Fused 2-layer MLP: h1=elu(X@W1+b1) in LDS; out=ACT2(h1@W2+b2), bf16 out.
// MODE 0: (M,K1) rows. MODE 3: (M,8) pad32.
// MODE 4: concat (A=(M,128) bf16 | agg): agg = affine( aggB(s0 sums, read+zero)
//         + CSR-s1 gather of h2e rows (f32 acc) ) with deg-shift; block 0
//         publishes scl/shf to sclW[64].
template<int K1, int K1P, int C1, int C2, int BM, int NWM, int NWC, int NWM2, int NWC2,
         int ACT2, bool STATS, int MODE>
__global__ __launch_bounds__(256) void mlp2_k(
    const unsigned short* __restrict__ A,
    const unsigned short* __restrict__ Wt1, const float* __restrict__ b1,
    const unsigned short* __restrict__ Wt2, const float* __restrict__ b2,
    unsigned short* __restrict__ out, int M, float* __restrict__ stat,
    unsigned short* __restrict__ aggB, const float* __restrict__ statP, float invE,
    const float* __restrict__ gg, const float* __restrict__ gb,
    float* __restrict__ sclW, const int* __restrict__ dg0, const int* __restrict__ dg1,
    const unsigned short* __restrict__ h2e, const int* __restrict__ off1,
    const int* __restrict__ eidx1)
{
  constexpr int FM  = BM / (16 * NWM);
  constexpr int FC  = C1 / (16 * NWC);
  constexpr int FM2 = BM / (16 * NWM2);
  constexpr int FC2 = C2 / (16 * NWC2);
  constexpr int NKS1 = K1P / 32;
  constexpr int NKS2 = C1 / 32;
  constexpr int AST = K1P + 8;
  constexpr int P1 = C1 + 8;
  constexpr int P2 = C2 + 8;
  constexpr int ACH = K1P / 8;
  static_assert(NWM * NWC == 4 && NWM2 * NWC2 == 4, "4 waves");
  static_assert(C2 <= C1, "repack reuses H1");

  __shared__ unsigned short As[BM * AST];
  __shared__ unsigned short H1[BM * P1];
  __shared__ float red[2][C2];
  __shared__ float s_scl[(MODE == 4) ? 32 : 1], s_shf[(MODE == 4) ? 32 : 1];

  const int tid = threadIdx.x;
  const int row0 = blockIdx.x * BM;
  const int wave = tid >> 6, lane = tid & 63;
  const int wm = wave % NWM, wc = wave / NWM;
  const int wm2 = wave % NWM2, wc2 = wave / NWM2;
  const int lr = lane & 15, kg = lane >> 4;

  if (STATS) for (int i = tid; i < 2 * C2; i += 256) ((float*)red)[i] = 0.f;

  if constexpr (MODE == 4) {
    if (tid < 32) {
      float su = 0.f, sq = 0.f;
      for (int s = 0; s < NSLOT; ++s) {
        su += statP[(size_t)s * SSTR + tid];
        sq += statP[(size_t)s * SSTR + 256 + tid];
      }
      float mu = su * invE;
      float var = sq * invE - mu * mu;
      float sc = rsqrtf(var + 1e-5f) * gg[tid];
      float sh = gb[tid] - mu * sc;
      s_scl[tid] = sc; s_shf[tid] = sh;
      if (blockIdx.x == 0) { sclW[tid] = sc; sclW[32 + tid] = sh; }
    }
    __syncthreads();
  }

  for (int idx = tid; idx < BM * ACH; idx += 256) {
    int m = idx / ACH, chk = idx % ACH;
    int kglob = chk * 8;
    int row = row0 + m;
    uint4 v = make_uint4(0, 0, 0, 0);
    if (row < M) {
      if constexpr (MODE == 0) {
        if (kglob + 8 <= K1) v = *(const uint4*)(A + (size_t)row * K1 + kglob);
      } else if constexpr (MODE == 3) {
        if (chk == 0) v = *(const uint4*)(A + (size_t)row * 8);
      } else {  // MODE 4: agg = aggB(s0, read+zero) + CSR s1 gather (f32)
        if (kglob < 128) {
          v = *(const uint4*)(A + (size_t)row * 128 + kglob);
        } else {
          int c0 = kglob - 128;
          unsigned short* ap = &aggB[(size_t)row * 32 + c0];
          uint4 av4 = *(uint4*)ap;
          *(uint4*)ap = make_uint4(0, 0, 0, 0);
          const unsigned short* avp = (const unsigned short*)&av4;
          float acc[8];
#pragma unroll
          for (int j = 0; j < 8; ++j) acc[j] = bf2f(avp[j]);
          int o1 = off1[row], d1v = dg1[row];
          for (int i = 0; i < d1v; ++i) {
            int e = eidx1[o1 + i];
            uint4 hv = *(const uint4*)&h2e[(size_t)e * 32 + c0];
            const unsigned short* hp = (const unsigned short*)&hv;
#pragma unroll
            for (int j = 0; j < 8; ++j) acc[j] += bf2f(hp[j]);
          }
          float d = (float)(dg0[row] + d1v);
          unsigned short* vp = (unsigned short*)&v;
#pragma unroll
          for (int j = 0; j < 8; ++j)
            vp[j] = f2bf(fmaf(s_scl[c0 + j], acc[j], d * s_shf[c0 + j]));
        }
      }
    }
    *(uint4*)&As[m * AST + chk * 8] = v;
  }
  __syncthreads();

  f32x4 acc1[FM][FC];
#pragma unroll
  for (int i = 0; i < FM; ++i)
#pragma unroll
    for (int j = 0; j < FC; ++j) acc1[i][j] = (f32x4){0.f, 0.f, 0.f, 0.f};

#pragma unroll
  for (int ks = 0; ks < NKS1; ++ks) {
    const int k0 = ks * 32;
    short8 af[FM], bfr[FC];
#pragma unroll
    for (int i = 0; i < FM; ++i) {
      int r = (wm * FM + i) * 16 + lr;
      af[i] = __builtin_bit_cast(short8, *(const uint4*)&As[r * AST + k0 + kg * 8]);
    }
#pragma unroll
    for (int j = 0; j < FC; ++j) {
      int c = (wc * FC + j) * 16 + lr;
      bfr[j] = __builtin_bit_cast(short8, *(const uint4*)&Wt1[(size_t)c * K1P + k0 + kg * 8]);
    }
#pragma unroll
    for (int i = 0; i < FM; ++i)
#pragma unroll
      for (int j = 0; j < FC; ++j)
        acc1[i][j] = __builtin_amdgcn_mfma_f32_16x16x32_bf16(af[i], bfr[j], acc1[i][j], 0, 0, 0);
  }

  {
    float bl1[FC];
#pragma unroll
    for (int j = 0; j < FC; ++j) bl1[j] = b1[(wc * FC + j) * 16 + lr];
#pragma unroll
    for (int i = 0; i < FM; ++i)
#pragma unroll
      for (int t = 0; t < 4; ++t) {
        int rl = (wm * FM + i) * 16 + kg * 4 + t;
#pragma unroll
        for (int j = 0; j < FC; ++j)
          H1[rl * P1 + (wc * FC + j) * 16 + lr] = f2bf(act_elu(acc1[i][j][t] + bl1[j]));
      }
  }
  __syncthreads();

  f32x4 acc2[FM2][FC2];
#pragma unroll
  for (int i = 0; i < FM2; ++i)
#pragma unroll
    for (int j = 0; j < FC2; ++j) acc2[i][j] = (f32x4){0.f, 0.f, 0.f, 0.f};

#pragma unroll
  for (int ks = 0; ks < NKS2; ++ks) {
    const int k0 = ks * 32;
    short8 af[FM2], bfr[FC2];
#pragma unroll
    for (int i = 0; i < FM2; ++i) {
      int r = (wm2 * FM2 + i) * 16 + lr;
      af[i] = __builtin_bit_cast(short8, *(const uint4*)&H1[r * P1 + k0 + kg * 8]);
    }
#pragma unroll
    for (int j = 0; j < FC2; ++j) {
      int c = (wc2 * FC2 + j) * 16 + lr;
      bfr[j] = __builtin_bit_cast(short8, *(const uint4*)&Wt2[(size_t)c * C1 + k0 + kg * 8]);
    }
#pragma unroll
    for (int i = 0; i < FM2; ++i)
#pragma unroll
      for (int j = 0; j < FC2; ++j)
        acc2[i][j] = __builtin_amdgcn_mfma_f32_16x16x32_bf16(af[i], bfr[j], acc2[i][j], 0, 0, 0);
  }
  __syncthreads();

  float psum[FC2], psq[FC2], bl2[FC2];
#pragma unroll
  for (int j = 0; j < FC2; ++j) {
    psum[j] = 0.f; psq[j] = 0.f;
    bl2[j] = b2[(wc2 * FC2 + j) * 16 + lr];
  }
#pragma unroll
  for (int i = 0; i < FM2; ++i)
#pragma unroll
    for (int t = 0; t < 4; ++t) {
      int rl = (wm2 * FM2 + i) * 16 + kg * 4 + t;
      bool ok = (row0 + rl) < M;
#pragma unroll
      for (int j = 0; j < FC2; ++j) {
        float v = acc2[i][j][t] + bl2[j];
        if (ACT2 == 1) v = act_elu(v);
        else if (ACT2 == 2) v = tanhf(v);
        if (STATS && ok) { psum[j] += v; psq[j] += v * v; }
        H1[rl * P2 + (wc2 * FC2 + j) * 16 + lr] = f2bf(v);
      }
    }
  if (STATS) {
#pragma unroll
    for (int j = 0; j < FC2; ++j) {
      int c = (wc2 * FC2 + j) * 16 + lr;
      atomicAdd(&red[0][c], psum[j]);
      atomicAdd(&red[1][c], psq[j]);
    }
  }
  __syncthreads();
  for (int idx = tid; idx < BM * (C2 / 8); idx += 256) {
    int r = idx / (C2 / 8), cc = idx % (C2 / 8);
    int row = row0 + r;
    if (row < M)
      *(uint4*)&out[(size_t)row * C2 + cc * 8] = *(const uint4*)&H1[r * P2 + cc * 8];
  }
  if (STATS) {
    float* st = stat + (size_t)(blockIdx.x & (NSLOT - 1)) * SSTR;
    for (int i = tid; i < C2; i += 256) {
      atomicAdd(&st[i], red[0][i]);
      atomicAdd(&st[256 + i], red[1][i]);
    }
  }
}

// ---------------------------------------------------------------------------
// Single-layer GEMM with BN-affine staging (K=128 fixed when BNST>0):
//   BNST 1: A = affine(h2); writeback to Aln; block0 publishes pubStat scl/shf.
//   BNST 2: A = Aln + affine(h2); writeback to Aln.
//   BNST 3: A = Aln + affine(h2); no writeback.
// DEC 1: fuse decoder layer-2 (C->2 via W2f/b2f) + pos/vel integrate + preds.
template<int K, int C, int BM, int NWM, int NWC, int ACT, int DEC, int BNST>
__global__ __launch_bounds__(256) void mgemm_k(
    const unsigned short* __restrict__ Ah2,
    unsigned short* __restrict__ Aln,
    const unsigned short* __restrict__ Wt, const float* __restrict__ bias,
    unsigned short* __restrict__ out, int M,
    const float* __restrict__ statP, float invN,
    const float* __restrict__ gv, const float* __restrict__ bev,
    const float* __restrict__ pubStat, const float* __restrict__ pubG,
    const float* __restrict__ pubBe, float invPub, float* __restrict__ pubW,
    const float* __restrict__ W2f, const float* __restrict__ b2f,
    float* __restrict__ pos, float* __restrict__ vel, float* __restrict__ preds)
{
  constexpr int FM = BM / (16 * NWM);
  constexpr int FC = C / (16 * NWC);
  constexpr int NKS = K / 32;
  constexpr int AST = K + 8;
  constexpr int P2 = C + 8;
  constexpr int ACH = K / 8;
  static_assert(NWM * NWC == 4, "4 waves");
  static_assert(BNST == 0 || K == 128, "BN staging assumes K=128");

  __shared__ unsigned short As[BM * AST];
  __shared__ unsigned short Ob[BM * P2];
  __shared__ float Wl[DEC ? 256 : 1];
  __shared__ float s_scl[BNST ? 128 : 1], s_shf[BNST ? 128 : 1];

  const int tid = threadIdx.x;
  const int row0 = blockIdx.x * BM;
  const int wave = tid >> 6, lane = tid & 63;
  const int wm = wave % NWM, wc = wave / NWM;
  const int lr = lane & 15, kg = lane >> 4;

  if constexpr (BNST > 0) {
    if (tid < 128) {
      float su = 0.f, sq = 0.f;
      for (int s = 0; s < NSLOT; ++s) {
        su += statP[(size_t)s * SSTR + tid];
        sq += statP[(size_t)s * SSTR + 256 + tid];
      }
      float mu = su * invN;
      float var = sq * invN - mu * mu;
      float sc = rsqrtf(var + 1e-5f) * gv[tid];
      s_scl[tid] = sc; s_shf[tid] = bev[tid] - mu * sc;
    }
    if constexpr (BNST == 1) {
      if (blockIdx.x == 0 && tid >= 128 && tid < 160) {
        int c = tid - 128;
        float su = 0.f, sq = 0.f;
        for (int s = 0; s < NSLOT; ++s) {
          su += pubStat[(size_t)s * SSTR + c];
          sq += pubStat[(size_t)s * SSTR + 256 + c];
        }
        float mu = su * invPub;
        float var = sq * invPub - mu * mu;
        float sc = rsqrtf(var + 1e-5f) * pubG[c];
        pubW[c] = sc; pubW[32 + c] = pubBe[c] - mu * sc;
      }
    }
    __syncthreads();
  }

  for (int idx = tid; idx < BM * ACH; idx += 256) {
    int m = idx / ACH, chk = idx % ACH;
    int kglob = chk * 8;
    int row = row0 + m;
    uint4 v = make_uint4(0, 0, 0, 0);
    if (row < M) {
      if constexpr (BNST == 0) {
        v = *(const uint4*)(Ah2 + (size_t)row * K + kglob);
      } else {
        uint4 h = *(const uint4*)(Ah2 + (size_t)row * 128 + kglob);
        const unsigned short* hp = (const unsigned short*)&h;
        float f[8];
#pragma unroll
        for (int j = 0; j < 8; ++j)
          f[j] = fmaf(bf2f(hp[j]), s_scl[kglob + j], s_shf[kglob + j]);
        if constexpr (BNST >= 2) {
          uint4 l = *(const uint4*)(Aln + (size_t)row * 128 + kglob);
          const unsigned short* lp = (const unsigned short*)&l;
#pragma unroll
          for (int j = 0; j < 8; ++j) f[j] += bf2f(lp[j]);
        }
        unsigned short* vp = (unsigned short*)&v;
#pragma unroll
        for (int j = 0; j < 8; ++j) vp[j] = f2bf(f[j]);
        if constexpr (BNST <= 2)
          *(uint4*)(Aln + (size_t)row * 128 + kglob) = v;
      }
    }
    *(uint4*)&As[m * AST + chk * 8] = v;
  }
  __syncthreads();

  f32x4 acc[FM][FC];
#pragma unroll
  for (int i = 0; i < FM; ++i)
#pragma unroll
    for (int j = 0; j < FC; ++j) acc[i][j] = (f32x4){0.f, 0.f, 0.f, 0.f};

#pragma unroll
  for (int ks = 0; ks < NKS; ++ks) {
    const int k0 = ks * 32;
    short8 af[FM], bfr[FC];
#pragma unroll
    for (int i = 0; i < FM; ++i) {
      int r = (wm * FM + i) * 16 + lr;
      af[i] = __builtin_bit_cast(short8, *(const uint4*)&As[r * AST + k0 + kg * 8]);
    }
#pragma unroll
    for (int j = 0; j < FC; ++j) {
      int c = (wc * FC + j) * 16 + lr;
      bfr[j] = __builtin_bit_cast(short8, *(const uint4*)&Wt[(size_t)c * K + k0 + kg * 8]);
    }
#pragma unroll
    for (int i = 0; i < FM; ++i)
#pragma unroll
      for (int j = 0; j < FC; ++j)
        acc[i][j] = __builtin_amdgcn_mfma_f32_16x16x32_bf16(af[i], bfr[j], acc[i][j], 0, 0, 0);
  }

  float bl[FC];
#pragma unroll
  for (int j = 0; j < FC; ++j) bl[j] = bias[(wc * FC + j) * 16 + lr];
#pragma unroll
  for (int i = 0; i < FM; ++i)
#pragma unroll
    for (int t = 0; t < 4; ++t) {
      int rl = (wm * FM + i) * 16 + kg * 4 + t;
#pragma unroll
      for (int j = 0; j < FC; ++j) {
        float v = acc[i][j][t] + bl[j];
        if (ACT == 1) v = act_elu(v);
        else if (ACT == 2) v = tanhf(v);
        Ob[rl * P2 + (wc * FC + j) * 16 + lr] = f2bf(v);
      }
    }
  if constexpr (DEC) Wl[tid] = W2f[tid];
  __syncthreads();
  if constexpr (DEC) {
    int rloc = tid >> 3, j = tid & 7;
    int row = row0 + rloc;
    float ax = 0.f, ay = 0.f;
#pragma unroll
    for (int kk = 0; kk < 16; ++kk) {
      int k = j + 8 * kk;
      float f = bf2f(Ob[rloc * P2 + k]);
      ax = fmaf(f, Wl[2 * k], ax);
      ay = fmaf(f, Wl[2 * k + 1], ay);
    }
    ax += __shfl_down(ax, 4, 8); ax += __shfl_down(ax, 2, 8); ax += __shfl_down(ax, 1, 8);
    ay += __shfl_down(ay, 4, 8); ay += __shfl_down(ay, 2, 8); ay += __shfl_down(ay, 1, 8);
    if (j == 0 && row < M) {
      float axx = ax + b2f[0], ayy = ay + b2f[1];
      float2 p = ((float2*)pos)[row], vv = ((float2*)vel)[row];
      p.x += axx; p.y += ayy; vv.x += axx; vv.y += ayy;
      ((float2*)pos)[row] = p; ((float2*)vel)[row] = vv;
      ((float2*)preds)[row] = p;
    }
  } else {
    for (int idx = tid; idx < BM * (C / 8); idx += 256) {
      int r = idx / (C / 8), cc = idx % (C / 8);
      int row = row0 + r;
      if (row < M)
        *(uint4*)&out[(size_t)row * C + cc * 8] = *(const uint4*)&Ob[r * P2 + cc * 8];
    }
  }
}

// ---------------------------------------------------------------------------
// ge edge kernel (edges sorted by s0): h2 = elu(elu(Ps + le@W1c + b1)@W2 + b2).
// le computed in staging: LE=1: affine_EE(e32ee); LE=2: + affine_GE(e32ge).
// s0-side only scatter (sorted segments, pk-bf16). h2 always stored to out.
template<int LE>
__global__ __launch_bounds__(256) void ge_edge_k(
    const unsigned short* __restrict__ Pb,    // (N,256) bf16
    const unsigned short* __restrict__ e32ee, // (E,32) raw ee output
    const unsigned short* __restrict__ e32ge, // (E,32) raw ge mp0 output (LE=2)
    const float* __restrict__ sclEE,          // [scl(32) | shf(32)]
    const float* __restrict__ sclGE,          // [scl(32) | shf(32)] (LE=2)
    const int* __restrict__ epP,
    const unsigned short* __restrict__ Wt1c,  // (128,32)
    const float* __restrict__ b1,
    const unsigned short* __restrict__ Wt2,   // (32,128)
    const float* __restrict__ b2,
    unsigned short* __restrict__ out,         // (E,32) bf16 h2 store
    unsigned short* __restrict__ aggB,        // (N,32) bf16 s0 accumulators
    float* __restrict__ stat)
{
  constexpr int BM = 64;
  constexpr int P1 = 136;
  __shared__ unsigned short Ps[BM * P1];
  __shared__ unsigned short As[BM * 40];
  __shared__ float red[2][32];
  __shared__ int eps[BM * 2];

  const int tid = threadIdx.x;
  const int e0 = blockIdx.x * BM;
  const int wave = tid >> 6, lane = tid & 63;
  const int lr = lane & 15, kg = lane >> 4;
  const int wm = wave & 1, wc = wave >> 1;

  uint4 g0[4], g1[4];
  int gm[4], gch[4];
#pragma unroll
  for (int t = 0; t < 4; ++t) {
    int idx = tid + 256 * t;
    int m = idx >> 4, ch = idx & 15;
    gm[t] = m; gch[t] = ch;
    int s0 = epP[2 * (e0 + m)];
    int s1 = epP[2 * (e0 + m) + 1];
    g0[t] = *(const uint4*)&Pb[(size_t)s0 * 256 + ch * 8];
    g1[t] = *(const uint4*)&Pb[(size_t)s1 * 256 + 128 + ch * 8];
  }

  if (tid < BM * 2) eps[tid] = epP[e0 * 2 + tid];
  {
    int m = tid >> 2, chk = tid & 3;
    size_t base = (size_t)(e0 + m) * 32 + chk * 8;
    uint4 ev = *(const uint4*)&e32ee[base];
    const unsigned short* epv = (const unsigned short*)&ev;
    uint4 ov;
    unsigned short* op = (unsigned short*)&ov;
    if constexpr (LE == 2) {
      uint4 gv2 = *(const uint4*)&e32ge[base];
      const unsigned short* gp = (const unsigned short*)&gv2;
#pragma unroll
      for (int j = 0; j < 8; ++j) {
        int c = chk * 8 + j;
        float le = fmaf(sclEE[c], bf2f(epv[j]), sclEE[32 + c])
                 + fmaf(sclGE[c], bf2f(gp[j]), sclGE[32 + c]);
        op[j] = f2bf(le);
      }
    } else {
#pragma unroll
      for (int j = 0; j < 8; ++j) {
        int c = chk * 8 + j;
        op[j] = f2bf(fmaf(sclEE[c], bf2f(epv[j]), sclEE[32 + c]));
      }
    }
    *(uint4*)&As[m * 40 + chk * 8] = ov;
  }
  short8 wf1[4];
#pragma unroll
  for (int j = 0; j < 4; ++j)
    wf1[j] = __builtin_bit_cast(short8, *(const uint4*)&Wt1c[(size_t)((wc * 4 + j) * 16 + lr) * 32 + kg * 8]);
  if (tid < 64) ((float*)red)[tid] = 0.f;
  __syncthreads();

  f32x4 acc1[2][4];
#pragma unroll
  for (int i = 0; i < 2; ++i)
#pragma unroll
    for (int j = 0; j < 4; ++j) acc1[i][j] = (f32x4){0.f, 0.f, 0.f, 0.f};
  {
    short8 af[2];
#pragma unroll
    for (int i = 0; i < 2; ++i)
      af[i] = __builtin_bit_cast(short8, *(const uint4*)&As[((wm * 2 + i) * 16 + lr) * 40 + kg * 8]);
#pragma unroll
    for (int i = 0; i < 2; ++i)
#pragma unroll
      for (int j = 0; j < 4; ++j)
        acc1[i][j] = __builtin_amdgcn_mfma_f32_16x16x32_bf16(af[i], wf1[j], acc1[i][j], 0, 0, 0);
  }

#pragma unroll
  for (int t = 0; t < 4; ++t) {
    uint4 o;
    const unsigned short* ap = (const unsigned short*)&g0[t];
    const unsigned short* bp = (const unsigned short*)&g1[t];
    unsigned short* op = (unsigned short*)&o;
#pragma unroll
    for (int j = 0; j < 8; ++j) op[j] = f2bf(bf2f(ap[j]) + bf2f(bp[j]));
    *(uint4*)&Ps[gm[t] * P1 + gch[t] * 8] = o;
  }
  __syncthreads();

  {
    float bl1[4];
#pragma unroll
    for (int j = 0; j < 4; ++j) bl1[j] = b1[(wc * 4 + j) * 16 + lr];
#pragma unroll
    for (int i = 0; i < 2; ++i)
#pragma unroll
      for (int t = 0; t < 4; ++t) {
        int rl = (wm * 2 + i) * 16 + kg * 4 + t;
#pragma unroll
        for (int j = 0; j < 4; ++j) {
          int a = rl * P1 + (wc * 4 + j) * 16 + lr;
          Ps[a] = f2bf(act_elu(acc1[i][j][t] + bl1[j] + bf2f(Ps[a])));
        }
      }
  }
  __syncthreads();

  f32x4 acc2[2];
  acc2[0] = (f32x4){0.f, 0.f, 0.f, 0.f};
  acc2[1] = (f32x4){0.f, 0.f, 0.f, 0.f};
  const int r2 = wave * 16 + lr;
#pragma unroll
  for (int ks = 0; ks < 4; ++ks) {
    int k0 = ks * 32;
    short8 a2 = __builtin_bit_cast(short8, *(const uint4*)&Ps[r2 * P1 + k0 + kg * 8]);
#pragma unroll
    for (int j = 0; j < 2; ++j) {
      short8 b2v = __builtin_bit_cast(short8, *(const uint4*)&Wt2[(size_t)(j * 16 + lr) * 128 + k0 + kg * 8]);
      acc2[j] = __builtin_amdgcn_mfma_f32_16x16x32_bf16(a2, b2v, acc2[j], 0, 0, 0);
    }
  }

  float psum[2] = {0.f, 0.f}, psq[2] = {0.f, 0.f};
  float bl2[2] = {b2[lr], b2[16 + lr]};
#pragma unroll
  for (int t = 0; t < 4; ++t) {
    int rl = wave * 16 + kg * 4 + t;
#pragma unroll
    for (int j = 0; j < 2; ++j) {
      float v = act_elu(acc2[j][t] + bl2[j]);
      psum[j] += v; psq[j] += v * v;
      As[rl * 40 + j * 16 + lr] = f2bf(v);
    }
  }
#pragma unroll
  for (int j = 0; j < 2; ++j) {
    atomicAdd(&red[0][j * 16 + lr], psum[j]);
    atomicAdd(&red[1][j * 16 + lr], psq[j]);
  }
  __syncthreads();
  {
    int m = tid >> 2, chk = tid & 3;
    *(uint4*)&out[(size_t)(e0 + m) * 32 + chk * 8] = *(const uint4*)&As[m * 40 + chk * 8];
  }
  // ---- s0-only packed-bf16 scatter (sorted segments) ----
  {
    int cp = tid & 15;           // channels 2cp, 2cp+1
    int gsel = tid >> 4;         // 16 groups x 4 rows
    int rbeg = gsel * 4;
    float a0 = 0.f, a1 = 0.f;
    int cur = eps[2 * rbeg];
#pragma unroll
    for (int r = 0; r < 4; ++r) {
      int row = rbeg + r;
      unsigned pv = *(const unsigned*)&As[row * 40 + 2 * cp];
      float v0 = bf2f((unsigned short)(pv & 0xFFFF));
      float v1 = bf2f((unsigned short)(pv >> 16));
      int s0 = eps[2 * row];
      if (s0 != cur) {
        atomic_pk_bf16(&aggB[(size_t)cur * 32 + 2 * cp], a0, a1);
        a0 = 0.f; a1 = 0.f; cur = s0;
      }
      a0 += v0; a1 += v1;
    }
    atomic_pk_bf16(&aggB[(size_t)cur * 32 + 2 * cp], a0, a1);
  }
  if (tid < 32) {
    float* st = stat + (size_t)(blockIdx.x & (NSLOT - 1)) * SSTR;
    atomicAdd(&st[tid], red[0][tid]);
    atomicAdd(&st[256 + tid], red[1][tid]);
  }
}

// Weight transposes f32 (K,C) -> bf16 (NROW,KP) zero-padded.
__global__ __launch_bounds__(256) void wtrans_all_k(
    const float* __restrict__ enW1, const float* __restrict__ enW2,
    const float* __restrict__ geW1, const float* __restrict__ geW2,
    const float* __restrict__ gnW1, const float* __restrict__ gnW2,
    const float* __restrict__ dW1,  const float* __restrict__ eeW1,
    const float* __restrict__ eeW2,
    unsigned short* __restrict__ enW1t, unsigned short* __restrict__ enW2t,
    unsigned short* __restrict__ gePt,  unsigned short* __restrict__ geCt,
    unsigned short* __restrict__ geW2t,
    unsigned short* __restrict__ gnW1t, unsigned short* __restrict__ gnW2t,
    unsigned short* __restrict__ dW1t,  unsigned short* __restrict__ eeW1t,
    unsigned short* __restrict__ eeW2t)
{
  int i = blockIdx.x * 256 + threadIdx.x;
#define SEG(Wsrc, Wdst, NROW, SRCS, KS, KP) \
  { int n = (NROW) * (KP); \
    if (i < n) { int c = i / (KP), k = i - c * (KP); \
      (Wdst)[i] = (k < (KS)) ? f2bf((Wsrc)[(size_t)k * (SRCS) + c]) : (unsigned short)0; return; } \
    i -= n; }
  SEG(enW1, enW1t, 128, 128, 40, 64)
  SEG(enW2, enW2t, 128, 128, 128, 128)
  SEG(geW1, gePt, 128, 128, 128, 128)
  SEG(geW1 + 128 * 128, gePt + 128 * 128, 128, 128, 128, 128)
  SEG(geW1 + 256 * 128, geCt, 128, 128, 32, 32)
  SEG(geW2, geW2t, 32, 32, 128, 128)
  SEG(gnW1, gnW1t, 256, 256, 160, 160)
  SEG(gnW2, gnW2t, 128, 128, 256, 256)
  SEG(dW1,  dW1t,  128, 128, 128, 128)
  SEG(eeW1, eeW1t, 32, 32, 6, 32)
  SEG(eeW2, eeW2t, 32, 32, 32, 32)
#undef SEG
}
constexpr int WT_TOTAL = 128*64 + 128*128 + 128*128 + 128*128 + 128*32 + 32*128
                       + 256*160 + 128*256 + 128*128 + 32*32 + 32*32;

// ---- CSR / permutation build ----
__global__ __launch_bounds__(256) void csr_count0_k(const int* __restrict__ ep,
    int* __restrict__ deg0, int E)
{
  int e = blockIdx.x * 256 + threadIdx.x;
  if (e < E) atomicAdd(&deg0[ep[2 * e]], 1);
}

__global__ __launch_bounds__(1024) void csr_scan_k(const int* __restrict__ deg,
    int* __restrict__ off, int* __restrict__ cursor, int N)
{
  __shared__ int part[1024];
  int t = threadIdx.x;
  const int CHK = (N + 1023) / 1024;
  int c0 = t * CHK, c1 = min(c0 + CHK, N);
  int s = 0;
  for (int i = c0; i < c1; ++i) s += deg[i];
  part[t] = s;
  __syncthreads();
  for (int o = 1; o < 1024; o <<= 1) {
    int v = (t >= o) ? part[t - o] : 0;
    __syncthreads();
    part[t] += v;
    __syncthreads();
  }
  int run = t ? part[t - 1] : 0;
  for (int i = c0; i < c1; ++i) { int d = deg[i]; off[i] = run; cursor[i] = run; run += d; }
}

__global__ __launch_bounds__(256) void csr_fill0_k(const int* __restrict__ ep,
    int* __restrict__ cursor0, int* __restrict__ perm, int E)
{
  int e = blockIdx.x * 256 + threadIdx.x;
  if (e < E) { int p = atomicAdd(&cursor0[ep[2 * e]], 1); perm[p] = e; }
}

__global__ __launch_bounds__(256) void permute_edges_k(const float4* __restrict__ nodes4,
    const float* __restrict__ attr, const int* __restrict__ ep,
    const int* __restrict__ perm, int* __restrict__ epP,
    unsigned short* __restrict__ efb, int* __restrict__ deg1, int E)
{
  int e2 = blockIdx.x * 256 + threadIdx.x;
  if (e2 >= E) return;
  int e = perm[e2];
  int s0 = ep[2 * e], s1 = ep[2 * e + 1];
  epP[2 * e2] = s0; epP[2 * e2 + 1] = s1;
  atomicAdd(&deg1[s1], 1);
  float4 w0 = nodes4[(size_t)10 * NN + s0];
  float4 w1 = nodes4[(size_t)10 * NN + s1];
  float2 a = ((const float2*)attr)[e];
  uint4 o;
  o.x = (unsigned)f2bf(a.x) | ((unsigned)f2bf(a.y) << 16);
  o.y = (unsigned)f2bf(fabsf(w0.x - w1.x)) | ((unsigned)f2bf(fabsf(w0.y - w1.y)) << 16);
  o.z = (unsigned)f2bf(fabsf(w0.z - w1.z)) | ((unsigned)f2bf(fabsf(w0.w - w1.w)) << 16);
  o.w = 0;
  ((uint4*)efb)[e2] = o;
}

__global__ __launch_bounds__(256) void csr_fill1_k(const int* __restrict__ epP,
    int* __restrict__ cursor1, int* __restrict__ eidx1, int E)
{
  int e = blockIdx.x * 256 + threadIdx.x;
  if (e < E) { int p = atomicAdd(&cursor1[epP[2 * e + 1]], 1); eidx1[p] = e; }
}

__global__ __launch_bounds__(256) void pd_upd_k(const float* __restrict__ pos,
    const int* __restrict__ epP, unsigned short* __restrict__ efb, int E)
{
  int e = blockIdx.x * 256 + threadIdx.x;
  if (e >= E) return;
  float2 p0 = ((const float2*)pos)[epP[2 * e]];
  float2 p1 = ((const float2*)pos)[epP[2 * e + 1]];
  unsigned u = (unsigned)f2bf(fabsf(p0.x - p1.x)) | ((unsigned)f2bf(fabsf(p0.y - p1.y)) << 16);
  *(unsigned*)&efb[(size_t)e * 8 + 4] = u;
}

__global__ __launch_bounds__(256) void hist_shift_k(float* __restrict__ hist,
    unsigned short* __restrict__ histb,
    const float* __restrict__ pos, const float* __restrict__ vel, int M)
{
  int n = blockIdx.x * 256 + threadIdx.x;
  if (n >= M) return;
  float4* h4 = (float4*)(hist + (size_t)n * 40);
  float4 tmp[10];
#pragma unroll
  for (int t = 0; t < 10; ++t) tmp[t] = h4[t];
  float2 pp = ((const float2*)pos)[n], vv = ((const float2*)vel)[n];
  unsigned* hb = (unsigned*)(histb + (size_t)n * 40);
#pragma unroll
  for (int t = 0; t < 9; ++t) {
    float4 v = tmp[t + 1];
    h4[t] = v;
    hb[2 * t]     = (unsigned)f2bf(v.x) | ((unsigned)f2bf(v.y) << 16);
    hb[2 * t + 1] = (unsigned)f2bf(v.z) | ((unsigned)f2bf(v.w) << 16);
  }
  float4 nv = make_float4(pp.x, pp.y, vv.x, vv.y);
  h4[9] = nv;
  hb[18] = (unsigned)f2bf(nv.x) | ((unsigned)f2bf(nv.y) << 16);
  hb[19] = (unsigned)f2bf(nv.z) | ((unsigned)f2bf(nv.w) << 16);
}

__global__ __launch_bounds__(256) void init_nodes_k(const float4* __restrict__ nodes4,
    float* __restrict__ hist, unsigned short* __restrict__ histb,
    float* __restrict__ pos, float* __restrict__ vel,
    float* __restrict__ outGt, int M)
{
  int n = blockIdx.x * 256 + threadIdx.x;
  if (n >= M) return;
  float4* h4 = (float4*)(hist + (size_t)n * 40);
  unsigned* hb = (unsigned*)(histb + (size_t)n * 40);
  float4 v;
#pragma unroll
  for (int t = 0; t < 10; ++t) {
    v = nodes4[(size_t)t * M + n];
    h4[t] = v;
    hb[2 * t]     = (unsigned)f2bf(v.x) | ((unsigned)f2bf(v.y) << 16);
    hb[2 * t + 1] = (unsigned)f2bf(v.z) | ((unsigned)f2bf(v.w) << 16);
  }
  ((float2*)pos)[n] = make_float2(v.x, v.y);
  ((float2*)vel)[n] = make_float2(v.z, v.w);
  float4 g0 = nodes4[(size_t)10 * M + n];
  float4 g1 = nodes4[(size_t)11 * M + n];
  float2* gt2 = (float2*)outGt;
  gt2[(size_t)2 * n + 0] = make_float2(g0.x, g0.y);
  gt2[(size_t)2 * n + 1] = make_float2(g0.z, g0.w);
  gt2[(size_t)2 * (M + n) + 0] = make_float2(g1.x, g1.y);
  gt2[(size_t)2 * (M + n) + 1] = make_float2(g1.z, g1.w);
}

__global__ __launch_bounds__(256) void loss_k(const float* __restrict__ preds,
    const float* __restrict__ gtf, float* __restrict__ acc)
{
  int i = blockIdx.x * 256 + threadIdx.x;
  float d2 = 0.f;
  if (i < 2 * NN * 2) {
    int r = i / (NN * 2);
    int rem = i - r * (NN * 2);
    int n = rem >> 1, c = rem & 1;
    float df = preds[i] - gtf[((size_t)r * NN + n) * 4 + c];
    d2 = df * df;
  }
#pragma unroll
  for (int o = 32; o > 0; o >>= 1) d2 += __shfl_down(d2, o, 64);
  __shared__ float sb[4];
  int lane = threadIdx.x & 63, w = threadIdx.x >> 6;
  if (lane == 0) sb[w] = d2;
  __syncthreads();
  if (threadIdx.x == 0) atomicAdd(acc, sb[0] + sb[1] + sb[2] + sb[3]);
}

__global__ void loss_write_k(const float* __restrict__ acc, float* __restrict__ o)
{
  float s = *acc;
  o[0] = s * 0.25f;
  o[1] = s * (1.f / 80000.f);
}

extern "C" void kernel_launch(void* const* d_in, const int* in_sizes, int n_in,
                              void* d_out, int out_size, void* d_ws, size_t ws_size,
                              hipStream_t stream)
{
  (void)in_sizes; (void)n_in; (void)out_size; (void)ws_size;
  const float* nodes = (const float*)d_in[0];
  const int*   ep    = (const int*)d_in[1];
  const float* eattr = (const float*)d_in[2];
  const float *en_W1 = (const float*)d_in[3],  *en_b1 = (const float*)d_in[4],
              *en_W2 = (const float*)d_in[5],  *en_b2 = (const float*)d_in[6],
              *en_g  = (const float*)d_in[7],  *en_be = (const float*)d_in[8];
  const float *ee_W1 = (const float*)d_in[9],  *ee_b1 = (const float*)d_in[10],
              *ee_W2 = (const float*)d_in[11], *ee_b2 = (const float*)d_in[12],
              *ee_g  = (const float*)d_in[13], *ee_be = (const float*)d_in[14];
  const float *ge_W1 = (const float*)d_in[15], *ge_b1 = (const float*)d_in[16],
              *ge_W2 = (const float*)d_in[17], *ge_b2 = (const float*)d_in[18],
              *ge_g  = (const float*)d_in[19], *ge_be = (const float*)d_in[20];
  const float *gn_W1 = (const float*)d_in[21], *gn_b1 = (const float*)d_in[22],
              *gn_W2 = (const float*)d_in[23], *gn_b2 = (const float*)d_in[24],
              *gn_g  = (const float*)d_in[25], *gn_be = (const float*)d_in[26];
  const float *d_W1  = (const float*)d_in[27], *d_b1  = (const float*)d_in[28],
              *d_W2  = (const float*)d_in[29], *d_b2  = (const float*)d_in[30];

  float* out = (float*)d_out;
  float* outPreds = out;
  float* outLoss  = out + 80000;
  float* outGt    = out + 80002;

  float* ws = (float*)d_ws;
  size_t off = 0;
  auto alloc = [&](size_t nf) { float* p = ws + off; off += (nf + 15) & ~(size_t)15; return p; };
  float* hist  = alloc((size_t)NN * 40);
  unsigned short* histb = (unsigned short*)alloc((size_t)NN * 20);
  unsigned short* efb   = (unsigned short*)alloc((size_t)NE * 4);
  unsigned short* lnb  = (unsigned short*)alloc((size_t)NN * 64);
  unsigned short* e32ee = (unsigned short*)alloc((size_t)NE * 16);  // ee raw / mp1 h2
  unsigned short* e32ge = (unsigned short*)alloc((size_t)NE * 16);  // ge mp0 h2
  unsigned short* Pb   = (unsigned short*)alloc((size_t)NN * 128);
  unsigned short* h2nb = (unsigned short*)alloc((size_t)NN * 64);
  unsigned short* aggB = (unsigned short*)alloc((size_t)NN * 16);   // (N,32) bf16 s0 sums
  float* pos   = alloc((size_t)NN * 2);
  float* vel   = alloc((size_t)NN * 2);
  unsigned short* enW1t = (unsigned short*)alloc(128 * 64 / 2);
  unsigned short* enW2t = (unsigned short*)alloc(128 * 128 / 2);
  unsigned short* gePt  = (unsigned short*)alloc(256 * 128 / 2);
  unsigned short* geCt  = (unsigned short*)alloc(128 * 32 / 2);
  unsigned short* geW2t = (unsigned short*)alloc(32 * 128 / 2);
  unsigned short* gnW1t = (unsigned short*)alloc(256 * 160 / 2);
  unsigned short* gnW2t = (unsigned short*)alloc(128 * 256 / 2);
  unsigned short* dW1t  = (unsigned short*)alloc(128 * 128 / 2);
  unsigned short* eeW1t = (unsigned short*)alloc(32 * 32 / 2);
  unsigned short* eeW2t = (unsigned short*)alloc(32 * 32 / 2);
  const size_t SLOTSZ = (size_t)NSLOT * SSTR;
  float* statArr = alloc(12 * SLOTSZ + 256 + 16);
  float* zerosF  = statArr + 12 * SLOTSZ;
  float* lacc    = zerosF + 256;
  float* sclshfEE = alloc(64);
  float* sclshfGE = alloc(64);
  int* deg0    = (int*)alloc(NN);
  int* off0    = (int*)alloc(NN);
  int* cursor0 = (int*)alloc(NN);
  int* deg1    = (int*)alloc(NN);
  int* off1    = (int*)alloc(NN);
  int* cursor1 = (int*)alloc(NN);
  int* perm    = (int*)alloc(NE);
  int* epP     = (int*)alloc(2 * (size_t)NE);
  int* eidx1   = (int*)alloc(NE);

  hipMemsetAsync(statArr, 0, (12 * SLOTSZ + 256 + 16) * sizeof(float), stream);
  hipMemsetAsync(deg0, 0, NN * sizeof(int), stream);
  hipMemsetAsync(deg1, 0, NN * sizeof(int), stream);
  hipMemsetAsync(aggB, 0, (size_t)NN * 32 * sizeof(unsigned short), stream);

  wtrans_all_k<<<(WT_TOTAL + 255) / 256, 256, 0, stream>>>(
      en_W1, en_W2, ge_W1, ge_W2, gn_W1, gn_W2, d_W1, ee_W1, ee_W2,
      enW1t, enW2t, gePt, geCt, geW2t, gnW1t, gnW2t, dW1t, eeW1t, eeW2t);

  init_nodes_k<<<(NN + 255) / 256, 256, 0, stream>>>((const float4*)nodes, hist, histb, pos, vel, outGt, NN);

  csr_count0_k<<<(NE + 255) / 256, 256, 0, stream>>>(ep, deg0, NE);
  csr_scan_k<<<1, 1024, 0, stream>>>(deg0, off0, cursor0, NN);
  csr_fill0_k<<<(NE + 255) / 256, 256, 0, stream>>>(ep, cursor0, perm, NE);
  permute_edges_k<<<(NE + 255) / 256, 256, 0, stream>>>(
      (const float4*)nodes, eattr, ep, perm, epP, efb, deg1, NE);
  csr_scan_k<<<1, 1024, 0, stream>>>(deg1, off1, cursor1, NN);
  csr_fill1_k<<<(NE + 255) / 256, 256, 0, stream>>>(epP, cursor1, eidx1, NE);

  const int GN32 = (NN + 31) / 32;
  const int GE128 = NE / 128;
  const int GE64 = NE / 64;
  const float invE = 1.f / NE;
  const float invN = 1.f / NN;

  for (int r = 0; r < 2; ++r) {
    float* sEN  = statArr + (size_t)(r * 6 + 0) * SLOTSZ;
    float* sEE  = statArr + (size_t)(r * 6 + 1) * SLOTSZ;
    float* sGE0 = statArr + (size_t)(r * 6 + 2) * SLOTSZ;
    float* sGN0 = statArr + (size_t)(r * 6 + 3) * SLOTSZ;
    float* sGE1 = statArr + (size_t)(r * 6 + 4) * SLOTSZ;
    float* sGN1 = statArr + (size_t)(r * 6 + 5) * SLOTSZ;

    // ---- encoders ----
    mlp2_k<40, 64, 128, 128, 32, 2, 2, 2, 2, 1, true, 0><<<GN32, 256, 0, stream>>>(
        histb, enW1t, en_b1, enW2t, en_b2, h2nb, NN, sEN,
        nullptr, nullptr, 0.f, nullptr, nullptr, nullptr, nullptr, nullptr,
        nullptr, nullptr, nullptr);
    mlp2_k<32, 32, 32, 32, 128, 4, 1, 4, 1, 1, true, 3><<<GE128, 256, 0, stream>>>(
        efb, eeW1t, ee_b1, eeW2t, ee_b2, e32ee, NE, sEE,
        nullptr, nullptr, 0.f, nullptr, nullptr, nullptr, nullptr, nullptr,
        nullptr, nullptr, nullptr);

    // ---- mp0 ----
    mgemm_k<128, 256, 32, 2, 2, 0, 0, 1><<<GN32, 256, 0, stream>>>(
        h2nb, lnb, gePt, zerosF, Pb, NN,
        sEN, invN, en_g, en_be,
        sEE, ee_g, ee_be, invE, sclshfEE,
        nullptr, nullptr, nullptr, nullptr, nullptr);
    ge_edge_k<1><<<GE64, 256, 0, stream>>>(Pb, e32ee, nullptr, sclshfEE, nullptr,
        epP, geCt, ge_b1, geW2t, ge_b2, e32ge, aggB, sGE0);
    mlp2_k<160, 160, 256, 128, 32, 2, 2, 2, 2, 1, true, 4><<<GN32, 256, 0, stream>>>(
        lnb, gnW1t, gn_b1, gnW2t, gn_b2, h2nb, NN, sGN0,
        aggB, sGE0, invE, ge_g, ge_be, sclshfGE, deg0, deg1,
        e32ge, off1, eidx1);

    // ---- mp1 (h2 stored in-place into e32ee: row-exclusive per block) ----
    mgemm_k<128, 256, 32, 2, 2, 0, 0, 2><<<GN32, 256, 0, stream>>>(
        h2nb, lnb, gePt, zerosF, Pb, NN,
        sGN0, invN, gn_g, gn_be,
        nullptr, nullptr, nullptr, 0.f, nullptr,
        nullptr, nullptr, nullptr, nullptr, nullptr);
    ge_edge_k<2><<<GE64, 256, 0, stream>>>(Pb, e32ee, e32ge, sclshfEE, sclshfGE,
        epP, geCt, ge_b1, geW2t, ge_b2, e32ee, aggB, sGE1);
    mlp2_k<160, 160, 256, 128, 32, 2, 2, 2, 2, 1, true, 4><<<GN32, 256, 0, stream>>>(
        lnb, gnW1t, gn_b1, gnW2t, gn_b2, h2nb, NN, sGN1,
        aggB, sGE1, invE, ge_g, ge_be, sclshfGE, deg0, deg1,
        e32ee, off1, eidx1);

    // ---- decoder: BNST=3 staging (lnb + affine_GN1(h2nb)) + fused layer2 ----
    mgemm_k<128, 128, 32, 2, 2, 2, 1, 3><<<GN32, 256, 0, stream>>>(
        h2nb, lnb, dW1t, d_b1, nullptr, NN,
        sGN1, invN, gn_g, gn_be,
        nullptr, nullptr, nullptr, 0.f, nullptr,
        d_W2, d_b2, pos, vel, outPreds + (size_t)r * NN * 2);

    if (r == 0) {
      pd_upd_k<<<(NE + 255) / 256, 256, 0, stream>>>(pos, epP, efb, NE);
      hist_shift_k<<<(NN + 255) / 256, 256, 0, stream>>>(hist, histb, pos, vel, NN);
    }
  }

  loss_k<<<(2 * NN * 2 + 255) / 256, 256, 0, stream>>>(outPreds, outGt, lacc);
  loss_write_k<<<1, 1, 0, stream>>>(lacc, outLoss);
}

// Round 14
// 715.006 us; speedup vs baseline: 1.2675x; 1.2675x over previous
//
#include <hip/hip_runtime.h>

// MeshGraphNet rollout, round 14: revert to round-12 structure (best: 716us) —
// both-side packed-bf16 scatter in ge_edge — with the "memory" clobber removed
// from the atomic asm (data deps preserved; allows unordered issue of the ~6
// atomics/thread). BN folded into consumer staging, factored ge, slotted
// stats, s0-sorted edges. N=20000, E=320000, ROLL=2, MP=2.

constexpr int NN = 20000;
constexpr int NE = 320000;
constexpr int NSLOT = 32;        // stat sub-slots (de-contend atomics)
constexpr int SSTR = 512;        // floats per sub-slot: [sum(<=256) | sumsq(<=256)]

typedef __attribute__((ext_vector_type(8))) short short8;
typedef __attribute__((ext_vector_type(4))) float f32x4;

__device__ __forceinline__ float act_elu(float x) { return x > 0.f ? x : __expf(x) - 1.f; }
__device__ __forceinline__ unsigned short f2bf(float f) {
  unsigned u = __builtin_bit_cast(unsigned, f);
  return (unsigned short)((u + 0x7FFFu + ((u >> 16) & 1u)) >> 16);
}
__device__ __forceinline__ float bf2f(unsigned short h) {
  unsigned u = ((unsigned)h) << 16; return __builtin_bit_cast(float, u);
}
// packed bf16 atomic add: adds (a,b) to two consecutive bf16 at addr (4B aligned).
// No "memory" clobber: data deps carried via operands; no in-kernel reader.
__device__ __forceinline__ void atomic_pk_bf16(unsigned short* addr, float a, float b) {
  unsigned v = (unsigned)f2bf(a) | ((unsigned)f2bf(b) << 16);
  asm volatile("global_atomic_pk_add_bf16 %0, %1, off"
               :: "v"(addr), "v"(v));
}

// ---------------------------------------------------------------------------
// Fused 2-layer MLP: h1=elu(X@W1+b1) in LDS; out=ACT2(h1@W2+b2), bf16 out.
// MODE 0: (M,K1) rows. MODE 3: (M,8) pad32.
// MODE 4: concat (A=(M,128) bf16 | BN-affine(aggB bf16 (M,32)) with deg-shift);
//         reads & re-zeros aggB; block 0 publishes scl/shf to sclW[64].
template<int K1, int K1P, int C1, int C2, int BM, int NWM, int NWC, int NWM2, int NWC2,
         int ACT2, bool STATS, int MODE>
__global__ __launch_bounds__(256) void mlp2_k(
    const unsigned short* __restrict__ A,
    const unsigned short* __restrict__ Wt1, const float* __restrict__ b1,
    const unsigned short* __restrict__ Wt2, const float* __restrict__ b2,
    unsigned short* __restrict__ out, int M, float* __restrict__ stat,
    unsigned short* __restrict__ aggB, const float* __restrict__ statP, float invE,
    const float* __restrict__ gg, const float* __restrict__ gb,
    float* __restrict__ sclW, const int* __restrict__ dg0, const int* __restrict__ dg1)
{
  constexpr int FM  = BM / (16 * NWM);
  constexpr int FC  = C1 / (16 * NWC);
  constexpr int FM2 = BM / (16 * NWM2);
  constexpr int FC2 = C2 / (16 * NWC2);
  constexpr int NKS1 = K1P / 32;
  constexpr int NKS2 = C1 / 32;
  constexpr int AST = K1P + 8;
  constexpr int P1 = C1 + 8;
  constexpr int P2 = C2 + 8;
  constexpr int ACH = K1P / 8;
  static_assert(NWM * NWC == 4 && NWM2 * NWC2 == 4, "4 waves");
  static_assert(C2 <= C1, "repack reuses H1");

  __shared__ unsigned short As[BM * AST];
  __shared__ unsigned short H1[BM * P1];
  __shared__ float red[2][C2];
  __shared__ float s_scl[(MODE == 4) ? 32 : 1], s_shf[(MODE == 4) ? 32 : 1];

  const int tid = threadIdx.x;
  const int row0 = blockIdx.x * BM;
  const int wave = tid >> 6, lane = tid & 63;
  const int wm = wave % NWM, wc = wave / NWM;
  const int wm2 = wave % NWM2, wc2 = wave / NWM2;
  const int lr = lane & 15, kg = lane >> 4;

  if (STATS) for (int i = tid; i < 2 * C2; i += 256) ((float*)red)[i] = 0.f;

  if constexpr (MODE == 4) {
    if (tid < 32) {
      float su = 0.f, sq = 0.f;
      for (int s = 0; s < NSLOT; ++s) {
        su += statP[(size_t)s * SSTR + tid];
        sq += statP[(size_t)s * SSTR + 256 + tid];
      }
      float mu = su * invE;
      float var = sq * invE - mu * mu;
      float sc = rsqrtf(var + 1e-5f) * gg[tid];
      float sh = gb[tid] - mu * sc;
      s_scl[tid] = sc; s_shf[tid] = sh;
      if (blockIdx.x == 0) { sclW[tid] = sc; sclW[32 + tid] = sh; }
    }
    __syncthreads();
  }

  for (int idx = tid; idx < BM * ACH; idx += 256) {
    int m = idx / ACH, chk = idx % ACH;
    int kglob = chk * 8;
    int row = row0 + m;
    uint4 v = make_uint4(0, 0, 0, 0);
    if (row < M) {
      if constexpr (MODE == 0) {
        if (kglob + 8 <= K1) v = *(const uint4*)(A + (size_t)row * K1 + kglob);
      } else if constexpr (MODE == 3) {
        if (chk == 0) v = *(const uint4*)(A + (size_t)row * 8);
      } else {  // MODE 4: agg part is bf16, read + zero
        if (kglob < 128) {
          v = *(const uint4*)(A + (size_t)row * 128 + kglob);
        } else {
          int c0 = kglob - 128;
          unsigned short* ap = &aggB[(size_t)row * 32 + c0];
          uint4 av4 = *(uint4*)ap;
          *(uint4*)ap = make_uint4(0, 0, 0, 0);
          const unsigned short* avp = (const unsigned short*)&av4;
          float d = (float)(dg0[row] + dg1[row]);
          unsigned short* vp = (unsigned short*)&v;
#pragma unroll
          for (int j = 0; j < 8; ++j)
            vp[j] = f2bf(fmaf(s_scl[c0 + j], bf2f(avp[j]), d * s_shf[c0 + j]));
        }
      }
    }
    *(uint4*)&As[m * AST + chk * 8] = v;
  }
  __syncthreads();

  f32x4 acc1[FM][FC];
#pragma unroll
  for (int i = 0; i < FM; ++i)
#pragma unroll
    for (int j = 0; j < FC; ++j) acc1[i][j] = (f32x4){0.f, 0.f, 0.f, 0.f};

#pragma unroll
  for (int ks = 0; ks < NKS1; ++ks) {
    const int k0 = ks * 32;
    short8 af[FM], bfr[FC];
#pragma unroll
    for (int i = 0; i < FM; ++i) {
      int r = (wm * FM + i) * 16 + lr;
      af[i] = __builtin_bit_cast(short8, *(const uint4*)&As[r * AST + k0 + kg * 8]);
    }
#pragma unroll
    for (int j = 0; j < FC; ++j) {
      int c = (wc * FC + j) * 16 + lr;
      bfr[j] = __builtin_bit_cast(short8, *(const uint4*)&Wt1[(size_t)c * K1P + k0 + kg * 8]);
    }
#pragma unroll
    for (int i = 0; i < FM; ++i)
#pragma unroll
      for (int j = 0; j < FC; ++j)
        acc1[i][j] = __builtin_amdgcn_mfma_f32_16x16x32_bf16(af[i], bfr[j], acc1[i][j], 0, 0, 0);
  }

  {
    float bl1[FC];
#pragma unroll
    for (int j = 0; j < FC; ++j) bl1[j] = b1[(wc * FC + j) * 16 + lr];
#pragma unroll
    for (int i = 0; i < FM; ++i)
#pragma unroll
      for (int t = 0; t < 4; ++t) {
        int rl = (wm * FM + i) * 16 + kg * 4 + t;
#pragma unroll
        for (int j = 0; j < FC; ++j)
          H1[rl * P1 + (wc * FC + j) * 16 + lr] = f2bf(act_elu(acc1[i][j][t] + bl1[j]));
      }
  }
  __syncthreads();

  f32x4 acc2[FM2][FC2];
#pragma unroll
  for (int i = 0; i < FM2; ++i)
#pragma unroll
    for (int j = 0; j < FC2; ++j) acc2[i][j] = (f32x4){0.f, 0.f, 0.f, 0.f};

#pragma unroll
  for (int ks = 0; ks < NKS2; ++ks) {
    const int k0 = ks * 32;
    short8 af[FM2], bfr[FC2];
#pragma unroll
    for (int i = 0; i < FM2; ++i) {
      int r = (wm2 * FM2 + i) * 16 + lr;
      af[i] = __builtin_bit_cast(short8, *(const uint4*)&H1[r * P1 + k0 + kg * 8]);
    }
#pragma unroll
    for (int j = 0; j < FC2; ++j) {
      int c = (wc2 * FC2 + j) * 16 + lr;
      bfr[j] = __builtin_bit_cast(short8, *(const uint4*)&Wt2[(size_t)c * C1 + k0 + kg * 8]);
    }
#pragma unroll
    for (int i = 0; i < FM2; ++i)
#pragma unroll
      for (int j = 0; j < FC2; ++j)
        acc2[i][j] = __builtin_amdgcn_mfma_f32_16x16x32_bf16(af[i], bfr[j], acc2[i][j], 0, 0, 0);
  }
  __syncthreads();

  float psum[FC2], psq[FC2], bl2[FC2];
#pragma unroll
  for (int j = 0; j < FC2; ++j) {
    psum[j] = 0.f; psq[j] = 0.f;
    bl2[j] = b2[(wc2 * FC2 + j) * 16 + lr];
  }
#pragma unroll
  for (int i = 0; i < FM2; ++i)
#pragma unroll
    for (int t = 0; t < 4; ++t) {
      int rl = (wm2 * FM2 + i) * 16 + kg * 4 + t;
      bool ok = (row0 + rl) < M;
#pragma unroll
      for (int j = 0; j < FC2; ++j) {
        float v = acc2[i][j][t] + bl2[j];
        if (ACT2 == 1) v = act_elu(v);
        else if (ACT2 == 2) v = tanhf(v);
        if (STATS && ok) { psum[j] += v; psq[j] += v * v; }
        H1[rl * P2 + (wc2 * FC2 + j) * 16 + lr] = f2bf(v);
      }
    }
  if (STATS) {
#pragma unroll
    for (int j = 0; j < FC2; ++j) {
      int c = (wc2 * FC2 + j) * 16 + lr;
      atomicAdd(&red[0][c], psum[j]);
      atomicAdd(&red[1][c], psq[j]);
    }
  }
  __syncthreads();
  for (int idx = tid; idx < BM * (C2 / 8); idx += 256) {
    int r = idx / (C2 / 8), cc = idx % (C2 / 8);
    int row = row0 + r;
    if (row < M)
      *(uint4*)&out[(size_t)row * C2 + cc * 8] = *(const uint4*)&H1[r * P2 + cc * 8];
  }
  if (STATS) {
    float* st = stat + (size_t)(blockIdx.x & (NSLOT - 1)) * SSTR;
    for (int i = tid; i < C2; i += 256) {
      atomicAdd(&st[i], red[0][i]);
      atomicAdd(&st[256 + i], red[1][i]);
    }
  }
}

// ---------------------------------------------------------------------------
// Single-layer GEMM with BN-affine staging (K=128 fixed when BNST>0):
//   BNST 1: A = affine(h2); writeback to Aln; block0 publishes pubStat scl/shf.
//   BNST 2: A = Aln + affine(h2); writeback to Aln.
//   BNST 3: A = Aln + affine(h2); no writeback.
// DEC 1: fuse decoder layer-2 (C->2 via W2f/b2f) + pos/vel integrate + preds.
template<int K, int C, int BM, int NWM, int NWC, int ACT, int DEC, int BNST>
__global__ __launch_bounds__(256) void mgemm_k(
    const unsigned short* __restrict__ Ah2,
    unsigned short* __restrict__ Aln,
    const unsigned short* __restrict__ Wt, const float* __restrict__ bias,
    unsigned short* __restrict__ out, int M,
    const float* __restrict__ statP, float invN,
    const float* __restrict__ gv, const float* __restrict__ bev,
    const float* __restrict__ pubStat, const float* __restrict__ pubG,
    const float* __restrict__ pubBe, float invPub, float* __restrict__ pubW,
    const float* __restrict__ W2f, const float* __restrict__ b2f,
    float* __restrict__ pos, float* __restrict__ vel, float* __restrict__ preds)
{
  constexpr int FM = BM / (16 * NWM);
  constexpr int FC = C / (16 * NWC);
  constexpr int NKS = K / 32;
  constexpr int AST = K + 8;
  constexpr int P2 = C + 8;
  constexpr int ACH = K / 8;
  static_assert(NWM * NWC == 4, "4 waves");
  static_assert(BNST == 0 || K == 128, "BN staging assumes K=128");

  __shared__ unsigned short As[BM * AST];
  __shared__ unsigned short Ob[BM * P2];
  __shared__ float Wl[DEC ? 256 : 1];
  __shared__ float s_scl[BNST ? 128 : 1], s_shf[BNST ? 128 : 1];

  const int tid = threadIdx.x;
  const int row0 = blockIdx.x * BM;
  const int wave = tid >> 6, lane = tid & 63;
  const int wm = wave % NWM, wc = wave / NWM;
  const int lr = lane & 15, kg = lane >> 4;

  if constexpr (BNST > 0) {
    if (tid < 128) {
      float su = 0.f, sq = 0.f;
      for (int s = 0; s < NSLOT; ++s) {
        su += statP[(size_t)s * SSTR + tid];
        sq += statP[(size_t)s * SSTR + 256 + tid];
      }
      float mu = su * invN;
      float var = sq * invN - mu * mu;
      float sc = rsqrtf(var + 1e-5f) * gv[tid];
      s_scl[tid] = sc; s_shf[tid] = bev[tid] - mu * sc;
    }
    if constexpr (BNST == 1) {
      if (blockIdx.x == 0 && tid >= 128 && tid < 160) {
        int c = tid - 128;
        float su = 0.f, sq = 0.f;
        for (int s = 0; s < NSLOT; ++s) {
          su += pubStat[(size_t)s * SSTR + c];
          sq += pubStat[(size_t)s * SSTR + 256 + c];
        }
        float mu = su * invPub;
        float var = sq * invPub - mu * mu;
        float sc = rsqrtf(var + 1e-5f) * pubG[c];
        pubW[c] = sc; pubW[32 + c] = pubBe[c] - mu * sc;
      }
    }
    __syncthreads();
  }

  for (int idx = tid; idx < BM * ACH; idx += 256) {
    int m = idx / ACH, chk = idx % ACH;
    int kglob = chk * 8;
    int row = row0 + m;
    uint4 v = make_uint4(0, 0, 0, 0);
    if (row < M) {
      if constexpr (BNST == 0) {
        v = *(const uint4*)(Ah2 + (size_t)row * K + kglob);
      } else {
        uint4 h = *(const uint4*)(Ah2 + (size_t)row * 128 + kglob);
        const unsigned short* hp = (const unsigned short*)&h;
        float f[8];
#pragma unroll
        for (int j = 0; j < 8; ++j)
          f[j] = fmaf(bf2f(hp[j]), s_scl[kglob + j], s_shf[kglob + j]);
        if constexpr (BNST >= 2) {
          uint4 l = *(const uint4*)(Aln + (size_t)row * 128 + kglob);
          const unsigned short* lp = (const unsigned short*)&l;
#pragma unroll
          for (int j = 0; j < 8; ++j) f[j] += bf2f(lp[j]);
        }
        unsigned short* vp = (unsigned short*)&v;
#pragma unroll
        for (int j = 0; j < 8; ++j) vp[j] = f2bf(f[j]);
        if constexpr (BNST <= 2)
          *(uint4*)(Aln + (size_t)row * 128 + kglob) = v;
      }
    }
    *(uint4*)&As[m * AST + chk * 8] = v;
  }
  __syncthreads();

  f32x4 acc[FM][FC];
#pragma unroll
  for (int i = 0; i < FM; ++i)
#pragma unroll
    for (int j = 0; j < FC; ++j) acc[i][j] = (f32x4){0.f, 0.f, 0.f, 0.f};

#pragma unroll
  for (int ks = 0; ks < NKS; ++ks) {
    const int k0 = ks * 32;
    short8 af[FM], bfr[FC];
#pragma unroll
    for (int i = 0; i < FM; ++i) {
      int r = (wm * FM + i) * 16 + lr;
      af[i] = __builtin_bit_cast(short8, *(const uint4*)&As[r * AST + k0 + kg * 8]);
    }
#pragma unroll
    for (int j = 0; j < FC; ++j) {
      int c = (wc * FC + j) * 16 + lr;
      bfr[j] = __builtin_bit_cast(short8, *(const uint4*)&Wt[(size_t)c * K + k0 + kg * 8]);
    }
#pragma unroll
    for (int i = 0; i < FM; ++i)
#pragma unroll
      for (int j = 0; j < FC; ++j)
        acc[i][j] = __builtin_amdgcn_mfma_f32_16x16x32_bf16(af[i], bfr[j], acc[i][j], 0, 0, 0);
  }

  float bl[FC];
#pragma unroll
  for (int j = 0; j < FC; ++j) bl[j] = bias[(wc * FC + j) * 16 + lr];
#pragma unroll
  for (int i = 0; i < FM; ++i)
#pragma unroll
    for (int t = 0; t < 4; ++t) {
      int rl = (wm * FM + i) * 16 + kg * 4 + t;
#pragma unroll
      for (int j = 0; j < FC; ++j) {
        float v = acc[i][j][t] + bl[j];
        if (ACT == 1) v = act_elu(v);
        else if (ACT == 2) v = tanhf(v);
        Ob[rl * P2 + (wc * FC + j) * 16 + lr] = f2bf(v);
      }
    }
  if constexpr (DEC) Wl[tid] = W2f[tid];
  __syncthreads();
  if constexpr (DEC) {
    int rloc = tid >> 3, j = tid & 7;
    int row = row0 + rloc;
    float ax = 0.f, ay = 0.f;
#pragma unroll
    for (int kk = 0; kk < 16; ++kk) {
      int k = j + 8 * kk;
      float f = bf2f(Ob[rloc * P2 + k]);
      ax = fmaf(f, Wl[2 * k], ax);
      ay = fmaf(f, Wl[2 * k + 1], ay);
    }
    ax += __shfl_down(ax, 4, 8); ax += __shfl_down(ax, 2, 8); ax += __shfl_down(ax, 1, 8);
    ay += __shfl_down(ay, 4, 8); ay += __shfl_down(ay, 2, 8); ay += __shfl_down(ay, 1, 8);
    if (j == 0 && row < M) {
      float axx = ax + b2f[0], ayy = ay + b2f[1];
      float2 p = ((float2*)pos)[row], vv = ((float2*)vel)[row];
      p.x += axx; p.y += ayy; vv.x += axx; vv.y += ayy;
      ((float2*)pos)[row] = p; ((float2*)vel)[row] = vv;
      ((float2*)preds)[row] = p;
    }
  } else {
    for (int idx = tid; idx < BM * (C / 8); idx += 256) {
      int r = idx / (C / 8), cc = idx % (C / 8);
      int row = row0 + r;
      if (row < M)
        *(uint4*)&out[(size_t)row * C + cc * 8] = *(const uint4*)&Ob[r * P2 + cc * 8];
    }
  }
}

// ---------------------------------------------------------------------------
// ge edge kernel (edges sorted by s0): h2 = elu(elu(Ps + le@W1c + b1)@W2 + b2).
// le computed in staging: LE=1: affine_EE(e32ee); LE=2: + affine_GE(e32ge).
// Scatters h2 sums into aggB via packed-bf16 atomics. WOUT: store h2 to out.
template<int LE, int WOUT>
__global__ __launch_bounds__(256) void ge_edge_k(
    const unsigned short* __restrict__ Pb,    // (N,256) bf16
    const unsigned short* __restrict__ e32ee, // (E,32) raw ee output
    const unsigned short* __restrict__ e32ge, // (E,32) raw ge mp0 output (LE=2)
    const float* __restrict__ sclEE,          // [scl(32) | shf(32)]
    const float* __restrict__ sclGE,          // [scl(32) | shf(32)] (LE=2)
    const int* __restrict__ epP,
    const unsigned short* __restrict__ Wt1c,  // (128,32)
    const float* __restrict__ b1,
    const unsigned short* __restrict__ Wt2,   // (32,128)
    const float* __restrict__ b2,
    unsigned short* __restrict__ out,         // (E,32) bf16
    unsigned short* __restrict__ aggB,        // (N,32) bf16 accumulators
    float* __restrict__ stat)
{
  constexpr int BM = 64;
  constexpr int P1 = 136;
  __shared__ unsigned short Ps[BM * P1];
  __shared__ unsigned short As[BM * 40];
  __shared__ float red[2][32];
  __shared__ int eps[BM * 2];

  const int tid = threadIdx.x;
  const int e0 = blockIdx.x * BM;
  const int wave = tid >> 6, lane = tid & 63;
  const int lr = lane & 15, kg = lane >> 4;
  const int wm = wave & 1, wc = wave >> 1;

  uint4 g0[4], g1[4];
  int gm[4], gch[4];
#pragma unroll
  for (int t = 0; t < 4; ++t) {
    int idx = tid + 256 * t;
    int m = idx >> 4, ch = idx & 15;
    gm[t] = m; gch[t] = ch;
    int s0 = epP[2 * (e0 + m)];
    int s1 = epP[2 * (e0 + m) + 1];
    g0[t] = *(const uint4*)&Pb[(size_t)s0 * 256 + ch * 8];
    g1[t] = *(const uint4*)&Pb[(size_t)s1 * 256 + 128 + ch * 8];
  }

  if (tid < BM * 2) eps[tid] = epP[e0 * 2 + tid];
  {
    int m = tid >> 2, chk = tid & 3;
    size_t base = (size_t)(e0 + m) * 32 + chk * 8;
    uint4 ev = *(const uint4*)&e32ee[base];
    const unsigned short* epv = (const unsigned short*)&ev;
    uint4 ov;
    unsigned short* op = (unsigned short*)&ov;
    if constexpr (LE == 2) {
      uint4 gv2 = *(const uint4*)&e32ge[base];
      const unsigned short* gp = (const unsigned short*)&gv2;
#pragma unroll
      for (int j = 0; j < 8; ++j) {
        int c = chk * 8 + j;
        float le = fmaf(sclEE[c], bf2f(epv[j]), sclEE[32 + c])
                 + fmaf(sclGE[c], bf2f(gp[j]), sclGE[32 + c]);
        op[j] = f2bf(le);
      }
    } else {
#pragma unroll
      for (int j = 0; j < 8; ++j) {
        int c = chk * 8 + j;
        op[j] = f2bf(fmaf(sclEE[c], bf2f(epv[j]), sclEE[32 + c]));
      }
    }
    *(uint4*)&As[m * 40 + chk * 8] = ov;
  }
  short8 wf1[4];
#pragma unroll
  for (int j = 0; j < 4; ++j)
    wf1[j] = __builtin_bit_cast(short8, *(const uint4*)&Wt1c[(size_t)((wc * 4 + j) * 16 + lr) * 32 + kg * 8]);
  if (tid < 64) ((float*)red)[tid] = 0.f;
  __syncthreads();

  f32x4 acc1[2][4];
#pragma unroll
  for (int i = 0; i < 2; ++i)
#pragma unroll
    for (int j = 0; j < 4; ++j) acc1[i][j] = (f32x4){0.f, 0.f, 0.f, 0.f};
  {
    short8 af[2];
#pragma unroll
    for (int i = 0; i < 2; ++i)
      af[i] = __builtin_bit_cast(short8, *(const uint4*)&As[((wm * 2 + i) * 16 + lr) * 40 + kg * 8]);
#pragma unroll
    for (int i = 0; i < 2; ++i)
#pragma unroll
      for (int j = 0; j < 4; ++j)
        acc1[i][j] = __builtin_amdgcn_mfma_f32_16x16x32_bf16(af[i], wf1[j], acc1[i][j], 0, 0, 0);
  }

#pragma unroll
  for (int t = 0; t < 4; ++t) {
    uint4 o;
    const unsigned short* ap = (const unsigned short*)&g0[t];
    const unsigned short* bp = (const unsigned short*)&g1[t];
    unsigned short* op = (unsigned short*)&o;
#pragma unroll
    for (int j = 0; j < 8; ++j) op[j] = f2bf(bf2f(ap[j]) + bf2f(bp[j]));
    *(uint4*)&Ps[gm[t] * P1 + gch[t] * 8] = o;
  }
  __syncthreads();

  {
    float bl1[4];
#pragma unroll
    for (int j = 0; j < 4; ++j) bl1[j] = b1[(wc * 4 + j) * 16 + lr];
#pragma unroll
    for (int i = 0; i < 2; ++i)
#pragma unroll
      for (int t = 0; t < 4; ++t) {
        int rl = (wm * 2 + i) * 16 + kg * 4 + t;
#pragma unroll
        for (int j = 0; j < 4; ++j) {
          int a = rl * P1 + (wc * 4 + j) * 16 + lr;
          Ps[a] = f2bf(act_elu(acc1[i][j][t] + bl1[j] + bf2f(Ps[a])));
        }
      }
  }
  __syncthreads();

  f32x4 acc2[2];
  acc2[0] = (f32x4){0.f, 0.f, 0.f, 0.f};
  acc2[1] = (f32x4){0.f, 0.f, 0.f, 0.f};
  const int r2 = wave * 16 + lr;
#pragma unroll
  for (int ks = 0; ks < 4; ++ks) {
    int k0 = ks * 32;
    short8 a2 = __builtin_bit_cast(short8, *(const uint4*)&Ps[r2 * P1 + k0 + kg * 8]);
#pragma unroll
    for (int j = 0; j < 2; ++j) {
      short8 b2v = __builtin_bit_cast(short8, *(const uint4*)&Wt2[(size_t)(j * 16 + lr) * 128 + k0 + kg * 8]);
      acc2[j] = __builtin_amdgcn_mfma_f32_16x16x32_bf16(a2, b2v, acc2[j], 0, 0, 0);
    }
  }

  float psum[2] = {0.f, 0.f}, psq[2] = {0.f, 0.f};
  float bl2[2] = {b2[lr], b2[16 + lr]};
#pragma unroll
  for (int t = 0; t < 4; ++t) {
    int rl = wave * 16 + kg * 4 + t;
#pragma unroll
    for (int j = 0; j < 2; ++j) {
      float v = act_elu(acc2[j][t] + bl2[j]);
      psum[j] += v; psq[j] += v * v;
      As[rl * 40 + j * 16 + lr] = f2bf(v);
    }
  }
#pragma unroll
  for (int j = 0; j < 2; ++j) {
    atomicAdd(&red[0][j * 16 + lr], psum[j]);
    atomicAdd(&red[1][j * 16 + lr], psq[j]);
  }
  __syncthreads();
  if (WOUT) {
    int m = tid >> 2, chk = tid & 3;
    *(uint4*)&out[(size_t)(e0 + m) * 32 + chk * 8] = *(const uint4*)&As[m * 40 + chk * 8];
  }
  // ---- packed-bf16 scatter: thread = (channel pair cp, 4-row group) ----
  {
    int cp = tid & 15;           // channels 2cp, 2cp+1
    int gsel = tid >> 4;         // 16 groups x 4 rows
    int rbeg = gsel * 4;
    float a0 = 0.f, a1 = 0.f;
    int cur = eps[2 * rbeg];
#pragma unroll
    for (int r = 0; r < 4; ++r) {
      int row = rbeg + r;
      unsigned pv = *(const unsigned*)&As[row * 40 + 2 * cp];
      float v0 = bf2f((unsigned short)(pv & 0xFFFF));
      float v1 = bf2f((unsigned short)(pv >> 16));
      int s0 = eps[2 * row];
      if (s0 != cur) {
        atomic_pk_bf16(&aggB[(size_t)cur * 32 + 2 * cp], a0, a1);
        a0 = 0.f; a1 = 0.f; cur = s0;
      }
      a0 += v0; a1 += v1;
      atomic_pk_bf16(&aggB[(size_t)eps[2 * row + 1] * 32 + 2 * cp], v0, v1);
    }
    atomic_pk_bf16(&aggB[(size_t)cur * 32 + 2 * cp], a0, a1);
  }
  if (tid < 32) {
    float* st = stat + (size_t)(blockIdx.x & (NSLOT - 1)) * SSTR;
    atomicAdd(&st[tid], red[0][tid]);
    atomicAdd(&st[256 + tid], red[1][tid]);
  }
}

// Weight transposes f32 (K,C) -> bf16 (NROW,KP) zero-padded.
__global__ __launch_bounds__(256) void wtrans_all_k(
    const float* __restrict__ enW1, const float* __restrict__ enW2,
    const float* __restrict__ geW1, const float* __restrict__ geW2,
    const float* __restrict__ gnW1, const float* __restrict__ gnW2,
    const float* __restrict__ dW1,  const float* __restrict__ eeW1,
    const float* __restrict__ eeW2,
    unsigned short* __restrict__ enW1t, unsigned short* __restrict__ enW2t,
    unsigned short* __restrict__ gePt,  unsigned short* __restrict__ geCt,
    unsigned short* __restrict__ geW2t,
    unsigned short* __restrict__ gnW1t, unsigned short* __restrict__ gnW2t,
    unsigned short* __restrict__ dW1t,  unsigned short* __restrict__ eeW1t,
    unsigned short* __restrict__ eeW2t)
{
  int i = blockIdx.x * 256 + threadIdx.x;
#define SEG(Wsrc, Wdst, NROW, SRCS, KS, KP) \
  { int n = (NROW) * (KP); \
    if (i < n) { int c = i / (KP), k = i - c * (KP); \
      (Wdst)[i] = (k < (KS)) ? f2bf((Wsrc)[(size_t)k * (SRCS) + c]) : (unsigned short)0; return; } \
    i -= n; }
  SEG(enW1, enW1t, 128, 128, 40, 64)
  SEG(enW2, enW2t, 128, 128, 128, 128)
  SEG(geW1, gePt, 128, 128, 128, 128)
  SEG(geW1 + 128 * 128, gePt + 128 * 128, 128, 128, 128, 128)
  SEG(geW1 + 256 * 128, geCt, 128, 128, 32, 32)
  SEG(geW2, geW2t, 32, 32, 128, 128)
  SEG(gnW1, gnW1t, 256, 256, 160, 160)
  SEG(gnW2, gnW2t, 128, 128, 256, 256)
  SEG(dW1,  dW1t,  128, 128, 128, 128)
  SEG(eeW1, eeW1t, 32, 32, 6, 32)
  SEG(eeW2, eeW2t, 32, 32, 32, 32)
#undef SEG
}
constexpr int WT_TOTAL = 128*64 + 128*128 + 128*128 + 128*128 + 128*32 + 32*128
                       + 256*160 + 128*256 + 128*128 + 32*32 + 32*32;

// ---- CSR / permutation build ----
__global__ __launch_bounds__(256) void csr_count0_k(const int* __restrict__ ep,
    int* __restrict__ deg0, int E)
{
  int e = blockIdx.x * 256 + threadIdx.x;
  if (e < E) atomicAdd(&deg0[ep[2 * e]], 1);
}

__global__ __launch_bounds__(1024) void csr_scan_k(const int* __restrict__ deg,
    int* __restrict__ off, int* __restrict__ cursor, int N)
{
  __shared__ int part[1024];
  int t = threadIdx.x;
  const int CHK = (N + 1023) / 1024;
  int c0 = t * CHK, c1 = min(c0 + CHK, N);
  int s = 0;
  for (int i = c0; i < c1; ++i) s += deg[i];
  part[t] = s;
  __syncthreads();
  for (int o = 1; o < 1024; o <<= 1) {
    int v = (t >= o) ? part[t - o] : 0;
    __syncthreads();
    part[t] += v;
    __syncthreads();
  }
  int run = t ? part[t - 1] : 0;
  for (int i = c0; i < c1; ++i) { int d = deg[i]; off[i] = run; cursor[i] = run; run += d; }
}

__global__ __launch_bounds__(256) void csr_fill0_k(const int* __restrict__ ep,
    int* __restrict__ cursor0, int* __restrict__ perm, int E)
{
  int e = blockIdx.x * 256 + threadIdx.x;
  if (e < E) { int p = atomicAdd(&cursor0[ep[2 * e]], 1); perm[p] = e; }
}

__global__ __launch_bounds__(256) void permute_edges_k(const float4* __restrict__ nodes4,
    const float* __restrict__ attr, const int* __restrict__ ep,
    const int* __restrict__ perm, int* __restrict__ epP,
    unsigned short* __restrict__ efb, int* __restrict__ deg1, int E)
{
  int e2 = blockIdx.x * 256 + threadIdx.x;
  if (e2 >= E) return;
  int e = perm[e2];
  int s0 = ep[2 * e], s1 = ep[2 * e + 1];
  epP[2 * e2] = s0; epP[2 * e2 + 1] = s1;
  atomicAdd(&deg1[s1], 1);
  float4 w0 = nodes4[(size_t)10 * NN + s0];
  float4 w1 = nodes4[(size_t)10 * NN + s1];
  float2 a = ((const float2*)attr)[e];
  uint4 o;
  o.x = (unsigned)f2bf(a.x) | ((unsigned)f2bf(a.y) << 16);
  o.y = (unsigned)f2bf(fabsf(w0.x - w1.x)) | ((unsigned)f2bf(fabsf(w0.y - w1.y)) << 16);
  o.z = (unsigned)f2bf(fabsf(w0.z - w1.z)) | ((unsigned)f2bf(fabsf(w0.w - w1.w)) << 16);
  o.w = 0;
  ((uint4*)efb)[e2] = o;
}

__global__ __launch_bounds__(256) void pd_upd_k(const float* __restrict__ pos,
    const int* __restrict__ epP, unsigned short* __restrict__ efb, int E)
{
  int e = blockIdx.x * 256 + threadIdx.x;
  if (e >= E) return;
  float2 p0 = ((const float2*)pos)[epP[2 * e]];
  float2 p1 = ((const float2*)pos)[epP[2 * e + 1]];
  unsigned u = (unsigned)f2bf(fabsf(p0.x - p1.x)) | ((unsigned)f2bf(fabsf(p0.y - p1.y)) << 16);
  *(unsigned*)&efb[(size_t)e * 8 + 4] = u;
}

__global__ __launch_bounds__(256) void hist_shift_k(float* __restrict__ hist,
    unsigned short* __restrict__ histb,
    const float* __restrict__ pos, const float* __restrict__ vel, int M)
{
  int n = blockIdx.x * 256 + threadIdx.x;
  if (n >= M) return;
  float4* h4 = (float4*)(hist + (size_t)n * 40);
  float4 tmp[10];
#pragma unroll
  for (int t = 0; t < 10; ++t) tmp[t] = h4[t];
  float2 pp = ((const float2*)pos)[n], vv = ((const float2*)vel)[n];
  unsigned* hb = (unsigned*)(histb + (size_t)n * 40);
#pragma unroll
  for (int t = 0; t < 9; ++t) {
    float4 v = tmp[t + 1];
    h4[t] = v;
    hb[2 * t]     = (unsigned)f2bf(v.x) | ((unsigned)f2bf(v.y) << 16);
    hb[2 * t + 1] = (unsigned)f2bf(v.z) | ((unsigned)f2bf(v.w) << 16);
  }
  float4 nv = make_float4(pp.x, pp.y, vv.x, vv.y);
  h4[9] = nv;
  hb[18] = (unsigned)f2bf(nv.x) | ((unsigned)f2bf(nv.y) << 16);
  hb[19] = (unsigned)f2bf(nv.z) | ((unsigned)f2bf(nv.w) << 16);
}

__global__ __launch_bounds__(256) void init_nodes_k(const float4* __restrict__ nodes4,
    float* __restrict__ hist, unsigned short* __restrict__ histb,
    float* __restrict__ pos, float* __restrict__ vel,
    float* __restrict__ outGt, int M)
{
  int n = blockIdx.x * 256 + threadIdx.x;
  if (n >= M) return;
  float4* h4 = (float4*)(hist + (size_t)n * 40);
  unsigned* hb = (unsigned*)(histb + (size_t)n * 40);
  float4 v;
#pragma unroll
  for (int t = 0; t < 10; ++t) {
    v = nodes4[(size_t)t * M + n];
    h4[t] = v;
    hb[2 * t]     = (unsigned)f2bf(v.x) | ((unsigned)f2bf(v.y) << 16);
    hb[2 * t + 1] = (unsigned)f2bf(v.z) | ((unsigned)f2bf(v.w) << 16);
  }
  ((float2*)pos)[n] = make_float2(v.x, v.y);
  ((float2*)vel)[n] = make_float2(v.z, v.w);
  float4 g0 = nodes4[(size_t)10 * M + n];
  float4 g1 = nodes4[(size_t)11 * M + n];
  float2* gt2 = (float2*)outGt;
  gt2[(size_t)2 * n + 0] = make_float2(g0.x, g0.y);
  gt2[(size_t)2 * n + 1] = make_float2(g0.z, g0.w);
  gt2[(size_t)2 * (M + n) + 0] = make_float2(g1.x, g1.y);
  gt2[(size_t)2 * (M + n) + 1] = make_float2(g1.z, g1.w);
}

__global__ __launch_bounds__(256) void loss_k(const float* __restrict__ preds,
    const float* __restrict__ gtf, float* __restrict__ acc)
{
  int i = blockIdx.x * 256 + threadIdx.x;
  float d2 = 0.f;
  if (i < 2 * NN * 2) {
    int r = i / (NN * 2);
    int rem = i - r * (NN * 2);
    int n = rem >> 1, c = rem & 1;
    float df = preds[i] - gtf[((size_t)r * NN + n) * 4 + c];
    d2 = df * df;
  }
#pragma unroll
  for (int o = 32; o > 0; o >>= 1) d2 += __shfl_down(d2, o, 64);
  __shared__ float sb[4];
  int lane = threadIdx.x & 63, w = threadIdx.x >> 6;
  if (lane == 0) sb[w] = d2;
  __syncthreads();
  if (threadIdx.x == 0) atomicAdd(acc, sb[0] + sb[1] + sb[2] + sb[3]);
}

__global__ void loss_write_k(const float* __restrict__ acc, float* __restrict__ o)
{
  float s = *acc;
  o[0] = s * 0.25f;
  o[1] = s * (1.f / 80000.f);
}

extern "C" void kernel_launch(void* const* d_in, const int* in_sizes, int n_in,
                              void* d_out, int out_size, void* d_ws, size_t ws_size,
                              hipStream_t stream)
{
  (void)in_sizes; (void)n_in; (void)out_size; (void)ws_size;
  const float* nodes = (const float*)d_in[0];
  const int*   ep    = (const int*)d_in[1];
  const float* eattr = (const float*)d_in[2];
  const float *en_W1 = (const float*)d_in[3],  *en_b1 = (const float*)d_in[4],
              *en_W2 = (const float*)d_in[5],  *en_b2 = (const float*)d_in[6],
              *en_g  = (const float*)d_in[7],  *en_be = (const float*)d_in[8];
  const float *ee_W1 = (const float*)d_in[9],  *ee_b1 = (const float*)d_in[10],
              *ee_W2 = (const float*)d_in[11], *ee_b2 = (const float*)d_in[12],
              *ee_g  = (const float*)d_in[13], *ee_be = (const float*)d_in[14];
  const float *ge_W1 = (const float*)d_in[15], *ge_b1 = (const float*)d_in[16],
              *ge_W2 = (const float*)d_in[17], *ge_b2 = (const float*)d_in[18],
              *ge_g  = (const float*)d_in[19], *ge_be = (const float*)d_in[20];
  const float *gn_W1 = (const float*)d_in[21], *gn_b1 = (const float*)d_in[22],
              *gn_W2 = (const float*)d_in[23], *gn_b2 = (const float*)d_in[24],
              *gn_g  = (const float*)d_in[25], *gn_be = (const float*)d_in[26];
  const float *d_W1  = (const float*)d_in[27], *d_b1  = (const float*)d_in[28],
              *d_W2  = (const float*)d_in[29], *d_b2  = (const float*)d_in[30];

  float* out = (float*)d_out;
  float* outPreds = out;
  float* outLoss  = out + 80000;
  float* outGt    = out + 80002;

  float* ws = (float*)d_ws;
  size_t off = 0;
  auto alloc = [&](size_t nf) { float* p = ws + off; off += (nf + 15) & ~(size_t)15; return p; };
  float* hist  = alloc((size_t)NN * 40);
  unsigned short* histb = (unsigned short*)alloc((size_t)NN * 20);
  unsigned short* efb   = (unsigned short*)alloc((size_t)NE * 4);
  unsigned short* lnb  = (unsigned short*)alloc((size_t)NN * 64);
  unsigned short* e32ee = (unsigned short*)alloc((size_t)NE * 16);  // ee raw out
  unsigned short* e32ge = (unsigned short*)alloc((size_t)NE * 16);  // ge mp0 raw out
  unsigned short* Pb   = (unsigned short*)alloc((size_t)NN * 128);
  unsigned short* h2nb = (unsigned short*)alloc((size_t)NN * 64);
  unsigned short* aggB = (unsigned short*)alloc((size_t)NN * 16);   // (N,32) bf16
  float* pos   = alloc((size_t)NN * 2);
  float* vel   = alloc((size_t)NN * 2);
  unsigned short* enW1t = (unsigned short*)alloc(128 * 64 / 2);
  unsigned short* enW2t = (unsigned short*)alloc(128 * 128 / 2);
  unsigned short* gePt  = (unsigned short*)alloc(256 * 128 / 2);
  unsigned short* geCt  = (unsigned short*)alloc(128 * 32 / 2);
  unsigned short* geW2t = (unsigned short*)alloc(32 * 128 / 2);
  unsigned short* gnW1t = (unsigned short*)alloc(256 * 160 / 2);
  unsigned short* gnW2t = (unsigned short*)alloc(128 * 256 / 2);
  unsigned short* dW1t  = (unsigned short*)alloc(128 * 128 / 2);
  unsigned short* eeW1t = (unsigned short*)alloc(32 * 32 / 2);
  unsigned short* eeW2t = (unsigned short*)alloc(32 * 32 / 2);
  const size_t SLOTSZ = (size_t)NSLOT * SSTR;
  float* statArr = alloc(12 * SLOTSZ + 256 + 16);
  float* zerosF  = statArr + 12 * SLOTSZ;
  float* lacc    = zerosF + 256;
  float* sclshfEE = alloc(64);
  float* sclshfGE = alloc(64);
  int* deg0    = (int*)alloc(NN);
  int* off0    = (int*)alloc(NN);
  int* cursor0 = (int*)alloc(NN);
  int* deg1    = (int*)alloc(NN);
  int* perm    = (int*)alloc(NE);
  int* epP     = (int*)alloc(2 * (size_t)NE);

  hipMemsetAsync(statArr, 0, (12 * SLOTSZ + 256 + 16) * sizeof(float), stream);
  hipMemsetAsync(deg0, 0, NN * sizeof(int), stream);
  hipMemsetAsync(deg1, 0, NN * sizeof(int), stream);
  hipMemsetAsync(aggB, 0, (size_t)NN * 32 * sizeof(unsigned short), stream);

  wtrans_all_k<<<(WT_TOTAL + 255) / 256, 256, 0, stream>>>(
      en_W1, en_W2, ge_W1, ge_W2, gn_W1, gn_W2, d_W1, ee_W1, ee_W2,
      enW1t, enW2t, gePt, geCt, geW2t, gnW1t, gnW2t, dW1t, eeW1t, eeW2t);

  init_nodes_k<<<(NN + 255) / 256, 256, 0, stream>>>((const float4*)nodes, hist, histb, pos, vel, outGt, NN);

  csr_count0_k<<<(NE + 255) / 256, 256, 0, stream>>>(ep, deg0, NE);
  csr_scan_k<<<1, 1024, 0, stream>>>(deg0, off0, cursor0, NN);
  csr_fill0_k<<<(NE + 255) / 256, 256, 0, stream>>>(ep, cursor0, perm, NE);
  permute_edges_k<<<(NE + 255) / 256, 256, 0, stream>>>(
      (const float4*)nodes, eattr, ep, perm, epP, efb, deg1, NE);

  const int GN32 = (NN + 31) / 32;
  const int GE128 = NE / 128;
  const int GE64 = NE / 64;
  const float invE = 1.f / NE;
  const float invN = 1.f / NN;

  for (int r = 0; r < 2; ++r) {
    float* sEN  = statArr + (size_t)(r * 6 + 0) * SLOTSZ;
    float* sEE  = statArr + (size_t)(r * 6 + 1) * SLOTSZ;
    float* sGE0 = statArr + (size_t)(r * 6 + 2) * SLOTSZ;
    float* sGN0 = statArr + (size_t)(r * 6 + 3) * SLOTSZ;
    float* sGE1 = statArr + (size_t)(r * 6 + 4) * SLOTSZ;
    float* sGN1 = statArr + (size_t)(r * 6 + 5) * SLOTSZ;

    // ---- encoders ----
    mlp2_k<40, 64, 128, 128, 32, 2, 2, 2, 2, 1, true, 0><<<GN32, 256, 0, stream>>>(
        histb, enW1t, en_b1, enW2t, en_b2, h2nb, NN, sEN,
        nullptr, nullptr, 0.f, nullptr, nullptr, nullptr, nullptr, nullptr);
    mlp2_k<32, 32, 32, 32, 128, 4, 1, 4, 1, 1, true, 3><<<GE128, 256, 0, stream>>>(
        efb, eeW1t, ee_b1, eeW2t, ee_b2, e32ee, NE, sEE,
        nullptr, nullptr, 0.f, nullptr, nullptr, nullptr, nullptr, nullptr);

    // ---- mp0 ----
    mgemm_k<128, 256, 32, 2, 2, 0, 0, 1><<<GN32, 256, 0, stream>>>(
        h2nb, lnb, gePt, zerosF, Pb, NN,
        sEN, invN, en_g, en_be,
        sEE, ee_g, ee_be, invE, sclshfEE,
        nullptr, nullptr, nullptr, nullptr, nullptr);
    ge_edge_k<1, 1><<<GE64, 256, 0, stream>>>(Pb, e32ee, nullptr, sclshfEE, nullptr,
        epP, geCt, ge_b1, geW2t, ge_b2, e32ge, aggB, sGE0);
    mlp2_k<160, 160, 256, 128, 32, 2, 2, 2, 2, 1, true, 4><<<GN32, 256, 0, stream>>>(
        lnb, gnW1t, gn_b1, gnW2t, gn_b2, h2nb, NN, sGN0,
        aggB, sGE0, invE, ge_g, ge_be, sclshfGE, deg0, deg1);

    // ---- mp1 ----
    mgemm_k<128, 256, 32, 2, 2, 0, 0, 2><<<GN32, 256, 0, stream>>>(
        h2nb, lnb, gePt, zerosF, Pb, NN,
        sGN0, invN, gn_g, gn_be,
        nullptr, nullptr, nullptr, 0.f, nullptr,
        nullptr, nullptr, nullptr, nullptr, nullptr);
    ge_edge_k<2, 0><<<GE64, 256, 0, stream>>>(Pb, e32ee, e32ge, sclshfEE, sclshfGE,
        epP, geCt, ge_b1, geW2t, ge_b2, nullptr, aggB, sGE1);
    mlp2_k<160, 160, 256, 128, 32, 2, 2, 2, 2, 1, true, 4><<<GN32, 256, 0, stream>>>(
        lnb, gnW1t, gn_b1, gnW2t, gn_b2, h2nb, NN, sGN1,
        aggB, sGE1, invE, ge_g, ge_be, sclshfGE, deg0, deg1);

    // ---- decoder: BNST=3 staging (lnb + affine_GN1(h2nb)) + fused layer2 ----
    mgemm_k<128, 128, 32, 2, 2, 2, 1, 3><<<GN32, 256, 0, stream>>>(
        h2nb, lnb, dW1t, d_b1, nullptr, NN,
        sGN1, invN, gn_g, gn_be,
        nullptr, nullptr, nullptr, 0.f, nullptr,
        d_W2, d_b2, pos, vel, outPreds + (size_t)r * NN * 2);

    if (r == 0) {
      pd_upd_k<<<(NE + 255) / 256, 256, 0, stream>>>(pos, epP, efb, NE);
      hist_shift_k<<<(NN + 255) / 256, 256, 0, stream>>>(hist, histb, pos, vel, NN);
    }
  }

  loss_k<<<(2 * NN * 2 + 255) / 256, 256, 0, stream>>>(outPreds, outGt, lacc);
  loss_write_k<<<1, 1, 0, stream>>>(lacc, outLoss);
}